// Round 6
// baseline (85.350 us; speedup 1.0000x reference)
//
#include <hip/hip_runtime.h>
#include <math.h>
#include <stdint.h>

#define NN 8192
#define DD 1024
#define KT 2048   // 2*D
#define HH 100
#define HP 128    // padded hidden
#define LCAP 512  // per-batch per-label list capacity (expected ~128)
#define NB 32     // batches

typedef short short8 __attribute__((ext_vector_type(8)));
typedef float f32x4 __attribute__((ext_vector_type(4)));

__device__ __forceinline__ short f2bf(float f) {
    uint32_t u = __builtin_bit_cast(uint32_t, f);
    u += 0x7FFF + ((u >> 16) & 1);   // round-to-nearest-even
    return (short)(u >> 16);
}

// W1 fp32 [2048][100] -> w1t bf16-bits [128][2048] (transposed, zero-padded cols)
__global__ __launch_bounds__(256) void prep_w1t(const float* __restrict__ W1,
                                                short* __restrict__ w1t)
{
    const int col = blockIdx.x;          // 0..127
    const int k0  = threadIdx.x * 8;     // 0..2040
    short8 r;
    if (col < HH) {
#pragma unroll
        for (int j = 0; j < 8; ++j) r[j] = f2bf(W1[(size_t)(k0 + j) * HH + col]);
    } else {
#pragma unroll
        for (int j = 0; j < 8; ++j) r[j] = 0;
    }
    *(short8*)(w1t + (size_t)col * KT + k0) = r;
}

// 512 threads = 8 waves per block; block owns 16 rows; wave w owns K-slice
// [w*256, w*256+256). LDS-reduce pre-activations, wave-0 epilogue pushes
// scores into per-batch pos/neg lists (global atomics).
// NOTE: plain __launch_bounds__(512) — the (512,4) variant forced 64 VGPR and
// ~20 MB of scratch spill per dispatch (R4 post-mortem).
__global__ __launch_bounds__(512) void encoder_mfma(
    const float* __restrict__ q, const float* __restrict__ x,
    const short* __restrict__ w1t,
    const float* __restrict__ b1, const float* __restrict__ W2,
    const float* __restrict__ b2,
    const int* __restrict__ bidx, const int* __restrict__ y,
    float* __restrict__ sp, float* __restrict__ sn,
    int* __restrict__ cnt1, int* __restrict__ cnt0)
{
    __shared__ float buf[7][16][HP + 4];
    const int t  = threadIdx.x;
    const int w  = t >> 6;           // wave 0..7
    const int l  = t & 63;
    const int lr = l & 15;           // A row / B col / C col
    const int lg = l >> 4;           // 0..3
    const int ko = lg * 8;           // k slot offset within 32-chunk
    const int r0 = blockIdx.x * 16;
    const int kbase = w << 8;        // 256-deep K slice

    const float* arow = (kbase < DD)
        ? (q + (size_t)(r0 + lr) * DD + kbase + ko)
        : (x + (size_t)(r0 + lr) * DD + (kbase - DD) + ko);
    const short* bbase = w1t + kbase + ko + (size_t)lr * KT;

    f32x4 acc[8];
#pragma unroll
    for (int tt = 0; tt < 8; ++tt) acc[tt] = (f32x4)0.f;

    auto loadA = [&](int step, float4& u, float4& v) {
        const float* p = arow + step * 32;
        u = *(const float4*)p;
        v = *(const float4*)(p + 4);
    };
    auto loadB = [&](int step, short8 B[8]) {
#pragma unroll
        for (int tt = 0; tt < 8; ++tt)
            B[tt] = *(const short8*)(bbase + step * 32 + (size_t)(tt * 16) * KT);
    };
    auto domfma = [&](const float4& u, const float4& v, short8 B[8]) {
        short8 a;
        a[0]=f2bf(u.x); a[1]=f2bf(u.y); a[2]=f2bf(u.z); a[3]=f2bf(u.w);
        a[4]=f2bf(v.x); a[5]=f2bf(v.y); a[6]=f2bf(v.z); a[7]=f2bf(v.w);
#pragma unroll
        for (int tt = 0; tt < 8; ++tt)
            acc[tt] = __builtin_amdgcn_mfma_f32_16x16x32_bf16(a, B[tt], acc[tt], 0, 0, 0);
    };

    // 2-stage software pipeline over the 8 K-chunks of this wave's slice
    float4 u0, v0, u1, v1;
    short8 B0[8], B1[8];
    loadA(0, u0, v0); loadB(0, B0);
#pragma unroll
    for (int i = 0; i < 3; ++i) {
        loadA(2*i + 1, u1, v1); loadB(2*i + 1, B1);
        domfma(u0, v0, B0);
        loadA(2*i + 2, u0, v0); loadB(2*i + 2, B0);
        domfma(u1, v1, B1);
    }
    loadA(7, u1, v1); loadB(7, B1);
    domfma(u0, v0, B0);
    domfma(u1, v1, B1);

    if (w > 0) {
#pragma unroll
        for (int tt = 0; tt < 8; ++tt)
#pragma unroll
            for (int r = 0; r < 4; ++r)
                buf[w - 1][lg * 4 + r][tt * 16 + lr] = acc[tt][r];
    }
    __syncthreads();
    if (w == 0) {
        // fold the other 7 waves' partials
#pragma unroll
        for (int tt = 0; tt < 8; ++tt)
#pragma unroll
            for (int r = 0; r < 4; ++r) {
                float hs = acc[tt][r];
#pragma unroll
                for (int wv = 0; wv < 7; ++wv)
                    hs += buf[wv][lg * 4 + r][tt * 16 + lr];
                acc[tt][r] = hs;
            }
        float bb[8], ww[8];
#pragma unroll
        for (int tt = 0; tt < 8; ++tt) {
            const int col = tt * 16 + lr;
            const bool vld = col < HH;
            bb[tt] = vld ? b1[col] : 0.f;
            ww[tt] = vld ? W2[col] : 0.f;
        }
        const float b2v = b2[0];
#pragma unroll
        for (int r = 0; r < 4; ++r) {
            float sum = 0.f;
#pragma unroll
            for (int tt = 0; tt < 8; ++tt) {
                float h = acc[tt][r] + bb[tt];
                sum = fmaf(fmaxf(h, 0.f), ww[tt], sum);
            }
            sum += __shfl_xor(sum, 1);
            sum += __shfl_xor(sum, 2);
            sum += __shfl_xor(sum, 4);
            sum += __shfl_xor(sum, 8);
            if (lr == 0) {
                const float sv = sum + b2v;
                const int i = r0 + lg * 4 + r;
                const int g = bidx[i];
                if (y[i]) {
                    int idx = atomicAdd(&cnt1[g], 1);
                    if (idx < LCAP) sp[g * LCAP + idx] = sv;
                } else {
                    int idx = atomicAdd(&cnt0[g], 1);
                    if (idx < LCAP) sn[g * LCAP + idx] = sv;
                }
            }
        }
    }
}

// grid = NB*8 blocks; block (g, sl) handles pos indices p ≡ sl (mod 8).
__global__ __launch_bounds__(256) void pairsum_kernel(
    const float* __restrict__ sp, const float* __restrict__ sn,
    const int* __restrict__ cnt1, const int* __restrict__ cnt0,
    float* __restrict__ partial)
{
    __shared__ float lsn[LCAP];
    __shared__ float lsp[64];
    __shared__ float wsum[4];
    const int g  = blockIdx.x >> 3;
    const int sl = blockIdx.x & 7;
    const int t  = threadIdx.x;
    const int n1 = min(cnt1[g], LCAP);
    const int n0 = min(cnt0[g], LCAP);
    for (int j = t; j < n0; j += 256) lsn[j] = sn[g * LCAP + j];
    const int np = (n1 > sl) ? ((n1 - sl + 7) >> 3) : 0;
    for (int j = t; j < np; j += 256) lsp[j] = sp[g * LCAP + sl + j * 8];
    __syncthreads();
    float acc = 0.f;
    const int total = np * n0;
    for (int u = t; u < total; u += 256) {
        const int ip = u / n0;
        const int j  = u - ip * n0;
        const float d  = lsn[j] - lsp[ip];          // s_neg - s_pos
        const float ad = fabsf(d);
        const float z  = __builtin_exp2f(-ad * 1.44269504f);
        acc += fmaxf(d, 0.f) + __builtin_log2f(1.f + z) * 0.69314718f;
    }
#pragma unroll
    for (int off = 32; off > 0; off >>= 1) acc += __shfl_xor(acc, off, 64);
    const int wid = t >> 6, lane = t & 63;
    if (lane == 0) wsum[wid] = acc;
    __syncthreads();
    if (t == 0) partial[blockIdx.x] = wsum[0] + wsum[1] + wsum[2] + wsum[3];
}

__global__ __launch_bounds__(256) void finalize_kernel(
    const float* __restrict__ partial,
    const int* __restrict__ cnt1, const int* __restrict__ cnt0,
    float* __restrict__ out)
{
    __shared__ float ws_[4], wc_[4];
    const int t = threadIdx.x;
    float sv = partial[t];   // 256 entries
    float cv = 0.f;
    if (t < NB) cv = (float)min(cnt1[t], LCAP) * (float)min(cnt0[t], LCAP);
#pragma unroll
    for (int off = 32; off > 0; off >>= 1) {
        sv += __shfl_xor(sv, off, 64);
        cv += __shfl_xor(cv, off, 64);
    }
    const int wid = t >> 6, lane = t & 63;
    if (lane == 0) { ws_[wid] = sv; wc_[wid] = cv; }
    __syncthreads();
    if (t == 0)
        out[0] = (ws_[0] + ws_[1] + ws_[2] + ws_[3]) /
                 (wc_[0] + wc_[1] + wc_[2] + wc_[3]);
}

extern "C" void kernel_launch(void* const* d_in, const int* in_sizes, int n_in,
                              void* d_out, int out_size, void* d_ws, size_t ws_size,
                              hipStream_t stream)
{
    const int*   b  = (const int*)d_in[0];
    const float* q  = (const float*)d_in[1];
    const float* x  = (const float*)d_in[2];
    const int*   y  = (const int*)d_in[3];
    const float* W1 = (const float*)d_in[4];
    const float* b1 = (const float*)d_in[5];
    const float* W2 = (const float*)d_in[6];
    const float* b2 = (const float*)d_in[7];
    float* out = (float*)d_out;

    char* base = (char*)d_ws;
    short* w1t     = (short*)base;                       // 512 KB
    float* sp      = (float*)(base + 524288);            // 64 KB
    float* sn      = (float*)(base + 524288 + 65536);    // 64 KB
    int*   cnt1    = (int*)(base + 524288 + 131072);     // 128 B
    int*   cnt0    = cnt1 + NB;                          // 128 B
    float* partial = (float*)(base + 524288 + 131072 + 256);  // 1 KB

    (void)hipMemsetAsync(cnt1, 0, 2 * NB * sizeof(int), stream);
    prep_w1t<<<HP, 256, 0, stream>>>(W1, w1t);
    encoder_mfma<<<NN / 16, 512, 0, stream>>>(q, x, w1t, b1, W2, b2,
                                              b, y, sp, sn, cnt1, cnt0);
    pairsum_kernel<<<NB * 8, 256, 0, stream>>>(sp, sn, cnt1, cnt0, partial);
    finalize_kernel<<<1, 256, 0, stream>>>(partial, cnt1, cnt0, out);
}

// Round 7
// 76.098 us; speedup vs baseline: 1.1216x; 1.1216x over previous
//
#include <hip/hip_runtime.h>
#include <math.h>
#include <stdint.h>

#define NN 8192
#define DD 1024
#define KT 2048   // 2*D
#define HH 100
#define HP 128    // padded hidden
#define LCAP 512
#define NB 32
#define BKC 64            // K-chunk (f32 elements)
#define NCH (KT / BKC)    // 32 chunks

typedef short short8 __attribute__((ext_vector_type(8)));
typedef float f32x4 __attribute__((ext_vector_type(4)));

__device__ __forceinline__ short f2bf(float f) {
    uint32_t u = __builtin_bit_cast(uint32_t, f);
    u += 0x7FFF + ((u >> 16) & 1);   // round-to-nearest-even
    return (short)(u >> 16);
}

// W1 fp32 [2048][100] -> w1t bf16-bits [128][2048] (transposed, zero-padded cols)
__global__ __launch_bounds__(256) void prep_w1t(const float* __restrict__ W1,
                                                short* __restrict__ w1t)
{
    const int col = blockIdx.x;          // 0..127
    const int k0  = threadIdx.x * 8;     // 0..2040
    short8 r;
    if (col < HH) {
#pragma unroll
        for (int j = 0; j < 8; ++j) r[j] = f2bf(W1[(size_t)(k0 + j) * HH + col]);
    } else {
#pragma unroll
        for (int j = 0; j < 8; ++j) r[j] = 0;
    }
    *(short8*)(w1t + (size_t)col * KT + k0) = r;
}

// Block: 256 thr / 4 waves; 16 rows, wave w owns cols [w*32, w*32+32).
// K walked sequentially in 32 chunks of 64. A: global->reg(depth2)->LDS dbuf
// (lgkm domain). B: L2->regs (vm domain, issued before A prefetch).
__global__ __launch_bounds__(256) void encoder_mfma(
    const float* __restrict__ q, const float* __restrict__ x,
    const short* __restrict__ w1t,
    const float* __restrict__ b1, const float* __restrict__ W2,
    const float* __restrict__ b2,
    const int* __restrict__ bidx, const int* __restrict__ y,
    float* __restrict__ sp, float* __restrict__ sn,
    int* __restrict__ cnt1, int* __restrict__ cnt0)
{
    __shared__ float As[2][16][68];   // stride 68 f32: conflict-free b128 phases
    __shared__ float fold[4][16];
    const int t  = threadIdx.x;
    const int w  = t >> 6;            // wave 0..3
    const int l  = t & 63;
    const int lr = l & 15;            // A row / C col-in-tile
    const int lg = l >> 4;            // k-group 0..3
    const int r0 = blockIdx.x * 16;

    // A staging: thread t loads 16B: row = t>>4, f4 = t&15
    const int srow = t >> 4;
    const int sf4  = t & 15;
    const float* qb = q + (size_t)(r0 + srow) * DD + sf4 * 4;
    const float* xb = x + (size_t)(r0 + srow) * DD + sf4 * 4;
    auto aptr = [&](int c) -> const float* {
        const int kc = c * BKC;
        return (kc < DD) ? (qb + kc) : (xb + (kc - DD));
    };

    // B: wave w covers cols w*32 + {tt*16 + lr}
    const short* bp0 = w1t + (size_t)(w * 32 + lr) * KT + lg * 8;
    const short* bp1 = bp0 + (size_t)16 * KT;

    f32x4 acc0 = (f32x4)0.f, acc1 = (f32x4)0.f;

    auto cvt8 = [&](f32x4 u, f32x4 v) {
        short8 a;
        a[0]=f2bf(u[0]); a[1]=f2bf(u[1]); a[2]=f2bf(u[2]); a[3]=f2bf(u[3]);
        a[4]=f2bf(v[0]); a[5]=f2bf(v[1]); a[6]=f2bf(v[2]); a[7]=f2bf(v[3]);
        return a;
    };

    // prologue: chunk 0 into buf0; chunk 1 into regs
    float4 ap = *(const float4*)aptr(0);
    *(float4*)&As[0][srow][sf4 * 4] = ap;
    float4 a_pre = *(const float4*)aptr(1);
    __syncthreads();

#pragma unroll 2
    for (int c = 0; c < NCH; ++c) {
        const int cur = c & 1;
        // B loads for chunk c (issued FIRST -> counted vmcnt leaves A flying)
        const int koff = c * BKC;
        short8 b00 = *(const short8*)(bp0 + koff);
        short8 b01 = *(const short8*)(bp0 + koff + 32);
        short8 b10 = *(const short8*)(bp1 + koff);
        short8 b11 = *(const short8*)(bp1 + koff + 32);
        // A prefetch chunk c+2
        const int cn = (c + 2 < NCH) ? (c + 2) : (NCH - 1);
        float4 a_nxt = *(const float4*)aptr(cn);
        // A fragments from LDS (lgkm domain)
        const float* ar = &As[cur][lr][lg * 8];
        f32x4 f0 = *(const f32x4*)ar;
        f32x4 f1 = *(const f32x4*)(ar + 4);
        f32x4 f2 = *(const f32x4*)(ar + 32);
        f32x4 f3 = *(const f32x4*)(ar + 36);
        short8 aa0 = cvt8(f0, f1);
        short8 aa1 = cvt8(f2, f3);
        acc0 = __builtin_amdgcn_mfma_f32_16x16x32_bf16(aa0, b00, acc0, 0, 0, 0);
        acc0 = __builtin_amdgcn_mfma_f32_16x16x32_bf16(aa1, b01, acc0, 0, 0, 0);
        acc1 = __builtin_amdgcn_mfma_f32_16x16x32_bf16(aa0, b10, acc1, 0, 0, 0);
        acc1 = __builtin_amdgcn_mfma_f32_16x16x32_bf16(aa1, b11, acc1, 0, 0, 0);
        __syncthreads();
        if (c + 1 < NCH) {
            *(float4*)&As[cur ^ 1][srow][sf4 * 4] = a_pre;  // chunk c+1
            a_pre = a_nxt;
        }
        __syncthreads();
    }

    // epilogue: relu + W2 partial dot over this wave's 32 cols
    const int c0 = w * 32 + lr;
    const int c1 = c0 + 16;
    const float bb0 = (c0 < HH) ? b1[c0] : 0.f;
    const float ww0 = (c0 < HH) ? W2[c0] : 0.f;
    const float bb1 = (c1 < HH) ? b1[c1] : 0.f;
    const float ww1 = (c1 < HH) ? W2[c1] : 0.f;
#pragma unroll
    for (int r = 0; r < 4; ++r) {
        float v = fmaf(fmaxf(acc0[r] + bb0, 0.f), ww0,
                       fmaxf(acc1[r] + bb1, 0.f) * ww1);
        v += __shfl_xor(v, 1);
        v += __shfl_xor(v, 2);
        v += __shfl_xor(v, 4);
        v += __shfl_xor(v, 8);
        if (lr == 0) fold[w][lg * 4 + r] = v;   // row = lg*4+r
    }
    __syncthreads();
    if (t < 16) {
        const float sv = fold[0][t] + fold[1][t] + fold[2][t] + fold[3][t] + b2[0];
        const int i = r0 + t;
        const int g = bidx[i];
        if (y[i]) {
            int idx = atomicAdd(&cnt1[g], 1);
            if (idx < LCAP) sp[g * LCAP + idx] = sv;
        } else {
            int idx = atomicAdd(&cnt0[g], 1);
            if (idx < LCAP) sn[g * LCAP + idx] = sv;
        }
    }
}

// grid = NB*8 blocks; block (g, sl) handles pos indices p ≡ sl (mod 8).
__global__ __launch_bounds__(256) void pairsum_kernel(
    const float* __restrict__ sp, const float* __restrict__ sn,
    const int* __restrict__ cnt1, const int* __restrict__ cnt0,
    float* __restrict__ partial)
{
    __shared__ float lsn[LCAP];
    __shared__ float lsp[64];
    __shared__ float wsum[4];
    const int g  = blockIdx.x >> 3;
    const int sl = blockIdx.x & 7;
    const int t  = threadIdx.x;
    const int n1 = min(cnt1[g], LCAP);
    const int n0 = min(cnt0[g], LCAP);
    for (int j = t; j < n0; j += 256) lsn[j] = sn[g * LCAP + j];
    const int np = (n1 > sl) ? ((n1 - sl + 7) >> 3) : 0;
    for (int j = t; j < np; j += 256) lsp[j] = sp[g * LCAP + sl + j * 8];
    __syncthreads();
    float acc = 0.f;
    const int total = np * n0;
    for (int u = t; u < total; u += 256) {
        const int ip = u / n0;
        const int j  = u - ip * n0;
        const float d  = lsn[j] - lsp[ip];          // s_neg - s_pos
        const float ad = fabsf(d);
        const float z  = __builtin_exp2f(-ad * 1.44269504f);
        acc += fmaxf(d, 0.f) + __builtin_log2f(1.f + z) * 0.69314718f;
    }
#pragma unroll
    for (int off = 32; off > 0; off >>= 1) acc += __shfl_xor(acc, off, 64);
    const int wid = t >> 6, lane = t & 63;
    if (lane == 0) wsum[wid] = acc;
    __syncthreads();
    if (t == 0) partial[blockIdx.x] = wsum[0] + wsum[1] + wsum[2] + wsum[3];
}

__global__ __launch_bounds__(256) void finalize_kernel(
    const float* __restrict__ partial,
    const int* __restrict__ cnt1, const int* __restrict__ cnt0,
    float* __restrict__ out)
{
    __shared__ float ws_[4], wc_[4];
    const int t = threadIdx.x;
    float sv = partial[t];   // 256 entries
    float cv = 0.f;
    if (t < NB) cv = (float)min(cnt1[t], LCAP) * (float)min(cnt0[t], LCAP);
#pragma unroll
    for (int off = 32; off > 0; off >>= 1) {
        sv += __shfl_xor(sv, off, 64);
        cv += __shfl_xor(cv, off, 64);
    }
    const int wid = t >> 6, lane = t & 63;
    if (lane == 0) { ws_[wid] = sv; wc_[wid] = cv; }
    __syncthreads();
    if (t == 0)
        out[0] = (ws_[0] + ws_[1] + ws_[2] + ws_[3]) /
                 (wc_[0] + wc_[1] + wc_[2] + wc_[3]);
}

extern "C" void kernel_launch(void* const* d_in, const int* in_sizes, int n_in,
                              void* d_out, int out_size, void* d_ws, size_t ws_size,
                              hipStream_t stream)
{
    const int*   b  = (const int*)d_in[0];
    const float* q  = (const float*)d_in[1];
    const float* x  = (const float*)d_in[2];
    const int*   y  = (const int*)d_in[3];
    const float* W1 = (const float*)d_in[4];
    const float* b1 = (const float*)d_in[5];
    const float* W2 = (const float*)d_in[6];
    const float* b2 = (const float*)d_in[7];
    float* out = (float*)d_out;

    char* base = (char*)d_ws;
    short* w1t     = (short*)base;                       // 512 KB
    float* sp      = (float*)(base + 524288);            // 64 KB
    float* sn      = (float*)(base + 524288 + 65536);    // 64 KB
    int*   cnt1    = (int*)(base + 524288 + 131072);     // 128 B
    int*   cnt0    = cnt1 + NB;                          // 128 B
    float* partial = (float*)(base + 524288 + 131072 + 256);  // 1 KB

    (void)hipMemsetAsync(cnt1, 0, 2 * NB * sizeof(int), stream);
    prep_w1t<<<HP, 256, 0, stream>>>(W1, w1t);
    encoder_mfma<<<NN / 16, 256, 0, stream>>>(q, x, w1t, b1, W2, b2,
                                              b, y, sp, sn, cnt1, cnt0);
    pairsum_kernel<<<NB * 8, 256, 0, stream>>>(sp, sn, cnt1, cnt0, partial);
    finalize_kernel<<<1, 256, 0, stream>>>(partial, cnt1, cnt0, out);
}

// Round 8
// 67.242 us; speedup vs baseline: 1.2693x; 1.1317x over previous
//
#include <hip/hip_runtime.h>
#include <math.h>
#include <stdint.h>

#define NN 8192
#define DD 1024
#define KT 2048   // 2*D
#define HH 100
#define HP 128    // padded hidden
#define LCAP 512
#define NB 32
#define BKC 64            // K-chunk (f32 elements)
#define NCH (KT / BKC)    // 32 chunks

typedef short bf16x8 __attribute__((ext_vector_type(8)));
typedef short bf16x4 __attribute__((ext_vector_type(4)));
typedef float f32x4 __attribute__((ext_vector_type(4)));

__device__ __forceinline__ short f2bf(float f) {
    uint32_t u = __builtin_bit_cast(uint32_t, f);
    u += 0x7FFF + ((u >> 16) & 1);   // round-to-nearest-even
    return (short)(u >> 16);
}

// W1 fp32 [2048][100] -> w1t bf16-bits [128][2048]; coalesced read + LDS transpose.
__global__ __launch_bounds__(256) void prep_w1t(const float* __restrict__ W1,
                                                short* __restrict__ w1t)
{
    __shared__ float ld[16][104];
    const int t  = threadIdx.x;
    const int k0 = blockIdx.x * 16;          // 128 blocks
    for (int i = t; i < 16 * HH; i += 256) {
        const int kk = i / HH, cc = i - kk * HH;
        ld[kk][cc] = W1[(size_t)(k0 + kk) * HH + cc];
    }
    __syncthreads();
    const int col = t >> 1, half = t & 1;    // 128 cols x 2 halves
    bf16x8 r;
#pragma unroll
    for (int j = 0; j < 8; ++j) {
        const int kk = half * 8 + j;
        r[j] = (col < HH) ? f2bf(ld[kk][col]) : (short)0;
    }
    *(bf16x8*)(w1t + (size_t)col * KT + k0 + half * 8) = r;
}

// Block: 256 thr / 4 waves; 16 rows; wave w owns cols [w*32, w*32+32).
// A: global->reg (2 bodies ahead) -> bf16 LDS triple-buffer (1 barrier/body,
// XOR-swizzled 8B slots, conflict-free). B: L2->reg double-buffer (1 body ahead).
__global__ __launch_bounds__(256) void encoder_mfma(
    const float* __restrict__ q, const float* __restrict__ x,
    const short* __restrict__ w1t,
    const float* __restrict__ b1, const float* __restrict__ W2,
    const float* __restrict__ b2,
    const int* __restrict__ bidx, const int* __restrict__ y,
    float* __restrict__ sp, float* __restrict__ sn,
    int* __restrict__ cnt1, int* __restrict__ cnt0)
{
    __shared__ short As[3][16][64];   // bf16, 8B-slot XOR swizzle
    __shared__ float fold[4][16];
    const int t  = threadIdx.x;
    const int w  = t >> 6;            // wave 0..3
    const int l  = t & 63;
    const int lr = l & 15;            // A row / C col-in-tile
    const int lg = l >> 4;            // k-group 0..3
    const int r0 = blockIdx.x * 16;

    // A staging: thread t loads float4 = k [sslot*4, +4) of row srow
    const int srow  = t >> 4;
    const int sslot = t & 15;
    const int wslot = sslot ^ srow;   // physical 8B slot
    const float* qb = q + (size_t)(r0 + srow) * DD + sslot * 4;
    const float* xb = x + (size_t)(r0 + srow) * DD + sslot * 4;
    auto aptr = [&](int c) -> const float* {
        const int kc = c * BKC;
        return (kc < DD) ? (qb + kc) : (xb + (kc - DD));
    };
    auto stage = [&](int buf, const float4& v) {
        bf16x4 s;
        s[0] = f2bf(v.x); s[1] = f2bf(v.y); s[2] = f2bf(v.z); s[3] = f2bf(v.w);
        *(bf16x4*)&As[buf][srow][wslot * 4] = s;
    };

    // read slots (physical), 4 x ds_read_b64 per body
    const int p0 = ((2 * lg)     ^ lr) * 4;
    const int p1 = ((2 * lg + 1) ^ lr) * 4;
    const int p2 = ((2 * lg + 8) ^ lr) * 4;
    const int p3 = ((2 * lg + 9) ^ lr) * 4;

    const short* bp0 = w1t + (size_t)(w * 32 + lr) * KT + lg * 8;
    const short* bp1 = bp0 + (size_t)16 * KT;

    f32x4 acc0 = (f32x4)0.f, acc1 = (f32x4)0.f;

    bf16x8 bA0, bA1, bA2, bA3, bB0, bB1, bB2, bB3;
#define LOADB(c, x0, x1, x2, x3)                         \
    { const int ko_ = (c) * BKC;                         \
      x0 = *(const bf16x8*)(bp0 + ko_);                  \
      x1 = *(const bf16x8*)(bp0 + ko_ + 32);             \
      x2 = *(const bf16x8*)(bp1 + ko_);                  \
      x3 = *(const bf16x8*)(bp1 + ko_ + 32); }

#define FRAGS_MFMA(rb, b0, b1_, b2_, b3_)                                   \
    { const short* ar = &As[rb][lr][0];                                     \
      bf16x4 g0 = *(const bf16x4*)(ar + p0);                                \
      bf16x4 g1 = *(const bf16x4*)(ar + p1);                                \
      bf16x4 g2 = *(const bf16x4*)(ar + p2);                                \
      bf16x4 g3 = *(const bf16x4*)(ar + p3);                                \
      bf16x8 aa0 = __builtin_shufflevector(g0, g1, 0,1,2,3,4,5,6,7);        \
      bf16x8 aa1 = __builtin_shufflevector(g2, g3, 0,1,2,3,4,5,6,7);        \
      acc0 = __builtin_amdgcn_mfma_f32_16x16x32_bf16(aa0, b0,  acc0, 0,0,0);\
      acc0 = __builtin_amdgcn_mfma_f32_16x16x32_bf16(aa1, b1_, acc0, 0,0,0);\
      acc1 = __builtin_amdgcn_mfma_f32_16x16x32_bf16(aa0, b2_, acc1, 0,0,0);\
      acc1 = __builtin_amdgcn_mfma_f32_16x16x32_bf16(aa1, b3_, acc1, 0,0,0); }

    // prologue: chunks 0,1 staged; A(2),A(3) in regs; B(0) in bA
    float4 t0 = *(const float4*)aptr(0);
    float4 t1 = *(const float4*)aptr(1);
    float4 rE = *(const float4*)aptr(2);
    float4 rO = *(const float4*)aptr(3);
    LOADB(0, bA0, bA1, bA2, bA3);
    stage(0, t0);
    stage(1, t1);
    __syncthreads();

    int rb = 0;
#pragma unroll 1
    for (int c = 0; c < NCH; c += 2) {
        // ---- even body: chunk c (B in bA), prefetch B(c+1)->bB ----
        { const int cn = c + 1 < NCH ? c + 1 : NCH - 1; LOADB(cn, bB0, bB1, bB2, bB3); }
        FRAGS_MFMA(rb, bA0, bA1, bA2, bA3);
        __syncthreads();
        { int wb = rb - 1; if (wb < 0) wb = 2;        // (rb+2)%3
          stage(wb, rE);                              // chunk c+2
          rE = *(const float4*)aptr(c + 4 < NCH ? c + 4 : NCH - 1); }
        rb = (rb == 2) ? 0 : rb + 1;
        // ---- odd body: chunk c+1 (B in bB), prefetch B(c+2)->bA ----
        { const int cn = c + 2 < NCH ? c + 2 : NCH - 1; LOADB(cn, bA0, bA1, bA2, bA3); }
        FRAGS_MFMA(rb, bB0, bB1, bB2, bB3);
        __syncthreads();
        { int wb = rb - 1; if (wb < 0) wb = 2;
          stage(wb, rO);                              // chunk c+3
          rO = *(const float4*)aptr(c + 5 < NCH ? c + 5 : NCH - 1); }
        rb = (rb == 2) ? 0 : rb + 1;
    }

    // epilogue: relu + W2 partial dot over this wave's 32 cols
    const int c0 = w * 32 + lr;
    const int c1 = c0 + 16;
    const float bb0 = (c0 < HH) ? b1[c0] : 0.f;
    const float ww0 = (c0 < HH) ? W2[c0] : 0.f;
    const float bb1 = (c1 < HH) ? b1[c1] : 0.f;
    const float ww1 = (c1 < HH) ? W2[c1] : 0.f;
#pragma unroll
    for (int r = 0; r < 4; ++r) {
        float v = fmaf(fmaxf(acc0[r] + bb0, 0.f), ww0,
                       fmaxf(acc1[r] + bb1, 0.f) * ww1);
        v += __shfl_xor(v, 1);
        v += __shfl_xor(v, 2);
        v += __shfl_xor(v, 4);
        v += __shfl_xor(v, 8);
        if (lr == 0) fold[w][lg * 4 + r] = v;
    }
    __syncthreads();
    if (t < 16) {
        const float sv = fold[0][t] + fold[1][t] + fold[2][t] + fold[3][t] + b2[0];
        const int i = r0 + t;
        const int g = bidx[i];
        if (y[i]) {
            int idx = atomicAdd(&cnt1[g], 1);
            if (idx < LCAP) sp[g * LCAP + idx] = sv;
        } else {
            int idx = atomicAdd(&cnt0[g], 1);
            if (idx < LCAP) sn[g * LCAP + idx] = sv;
        }
    }
#undef LOADB
#undef FRAGS_MFMA
}

// grid = NB*8 blocks; block (g, sl) handles pos indices p ≡ sl (mod 8).
__global__ __launch_bounds__(256) void pairsum_kernel(
    const float* __restrict__ sp, const float* __restrict__ sn,
    const int* __restrict__ cnt1, const int* __restrict__ cnt0,
    float* __restrict__ partial)
{
    __shared__ float lsn[LCAP];
    __shared__ float lsp[64];
    __shared__ float wsum[4];
    const int g  = blockIdx.x >> 3;
    const int sl = blockIdx.x & 7;
    const int t  = threadIdx.x;
    const int n1 = min(cnt1[g], LCAP);
    const int n0 = min(cnt0[g], LCAP);
    for (int j = t; j < n0; j += 256) lsn[j] = sn[g * LCAP + j];
    const int np = (n1 > sl) ? ((n1 - sl + 7) >> 3) : 0;
    for (int j = t; j < np; j += 256) lsp[j] = sp[g * LCAP + sl + j * 8];
    __syncthreads();
    float acc = 0.f;
    const int total = np * n0;
    for (int u = t; u < total; u += 256) {
        const int ip = u / n0;
        const int j  = u - ip * n0;
        const float d  = lsn[j] - lsp[ip];          // s_neg - s_pos
        const float ad = fabsf(d);
        const float z  = __builtin_exp2f(-ad * 1.44269504f);
        acc += fmaxf(d, 0.f) + __builtin_log2f(1.f + z) * 0.69314718f;
    }
#pragma unroll
    for (int off = 32; off > 0; off >>= 1) acc += __shfl_xor(acc, off, 64);
    const int wid = t >> 6, lane = t & 63;
    if (lane == 0) wsum[wid] = acc;
    __syncthreads();
    if (t == 0) partial[blockIdx.x] = wsum[0] + wsum[1] + wsum[2] + wsum[3];
}

__global__ __launch_bounds__(256) void finalize_kernel(
    const float* __restrict__ partial,
    const int* __restrict__ cnt1, const int* __restrict__ cnt0,
    float* __restrict__ out)
{
    __shared__ float ws_[4], wc_[4];
    const int t = threadIdx.x;
    float sv = partial[t];   // 256 entries
    float cv = 0.f;
    if (t < NB) cv = (float)min(cnt1[t], LCAP) * (float)min(cnt0[t], LCAP);
#pragma unroll
    for (int off = 32; off > 0; off >>= 1) {
        sv += __shfl_xor(sv, off, 64);
        cv += __shfl_xor(cv, off, 64);
    }
    const int wid = t >> 6, lane = t & 63;
    if (lane == 0) { ws_[wid] = sv; wc_[wid] = cv; }
    __syncthreads();
    if (t == 0)
        out[0] = (ws_[0] + ws_[1] + ws_[2] + ws_[3]) /
                 (wc_[0] + wc_[1] + wc_[2] + wc_[3]);
}

extern "C" void kernel_launch(void* const* d_in, const int* in_sizes, int n_in,
                              void* d_out, int out_size, void* d_ws, size_t ws_size,
                              hipStream_t stream)
{
    const int*   b  = (const int*)d_in[0];
    const float* q  = (const float*)d_in[1];
    const float* x  = (const float*)d_in[2];
    const int*   y  = (const int*)d_in[3];
    const float* W1 = (const float*)d_in[4];
    const float* b1 = (const float*)d_in[5];
    const float* W2 = (const float*)d_in[6];
    const float* b2 = (const float*)d_in[7];
    float* out = (float*)d_out;

    char* base = (char*)d_ws;
    short* w1t     = (short*)base;                       // 512 KB
    float* sp      = (float*)(base + 524288);            // 64 KB
    float* sn      = (float*)(base + 524288 + 65536);    // 64 KB
    int*   cnt1    = (int*)(base + 524288 + 131072);     // 128 B
    int*   cnt0    = cnt1 + NB;                          // 128 B
    float* partial = (float*)(base + 524288 + 131072 + 256);  // 1 KB

    (void)hipMemsetAsync(cnt1, 0, 2 * NB * sizeof(int), stream);
    prep_w1t<<<HP, 256, 0, stream>>>(W1, w1t);
    encoder_mfma<<<NN / 16, 256, 0, stream>>>(q, x, w1t, b1, W2, b2,
                                              b, y, sp, sn, cnt1, cnt0);
    pairsum_kernel<<<NB * 8, 256, 0, stream>>>(sp, sn, cnt1, cnt0, partial);
    finalize_kernel<<<1, 256, 0, stream>>>(partial, cnt1, cnt0, out);
}

// Round 9
// 58.256 us; speedup vs baseline: 1.4651x; 1.1543x over previous
//
#include <hip/hip_runtime.h>
#include <math.h>
#include <stdint.h>

#define NN 8192
#define DD 1024
#define KT 2048   // 2*D
#define HH 100
#define HP 128    // padded hidden
#define LCAP 512
#define NB 32
#define BKC 64            // K per body (2 MFMA k-chunks)
#define NCH (KT / BKC)    // 32 bodies

typedef short bf16x8 __attribute__((ext_vector_type(8)));
typedef short bf16x4 __attribute__((ext_vector_type(4)));
typedef float f32x4 __attribute__((ext_vector_type(4)));

__device__ __forceinline__ short f2bf(float f) {
    uint32_t u = __builtin_bit_cast(uint32_t, f);
    u += 0x7FFF + ((u >> 16) & 1);   // round-to-nearest-even
    return (short)(u >> 16);
}

// W1 fp32 [2048][100] -> w1p packed fragments:
// w1p[((c32*8 + tile)*64 + lane)*8 + j] = bf16(W1[c32*32 + (lane>>4)*8 + j][tile*16 + (lane&15)])
// One B-fragment load = 64 lanes x 16B contiguous (fully coalesced).
__global__ __launch_bounds__(256) void prep_w1p(const float* __restrict__ W1,
                                                short* __restrict__ w1p)
{
    __shared__ float ld[32][104];
    const int t  = threadIdx.x;
    const int k0 = blockIdx.x * 32;          // 64 blocks
    for (int i = t; i < 32 * HH; i += 256) {
        const int kk = i / HH, cc = i - kk * HH;
        ld[kk][cc] = W1[(size_t)(k0 + kk) * HH + cc];
    }
    __syncthreads();
    for (int idx = t; idx < 512; idx += 256) {
        const int tt = idx >> 6, l = idx & 63;
        const int lr = l & 15, lg = l >> 4;
        const int col = tt * 16 + lr;
        bf16x8 r;
#pragma unroll
        for (int j = 0; j < 8; ++j)
            r[j] = (col < HH) ? f2bf(ld[lg * 8 + j][col]) : (short)0;
        *(bf16x8*)(w1p + ((size_t)(blockIdx.x * 8 + tt) * 64 + l) * 8) = r;
    }
}

// Block: 256 thr / 4 waves; 16 rows; wave w owns cols [w*32, w*32+32) = tiles {2w, 2w+1}.
// A: global->reg (2 bodies ahead) -> bf16 LDS triple-buffer (1 barrier/body, swizzled).
// B: packed-coalesced loads, register double-buffer (1 body ahead).
__global__ __launch_bounds__(256) void encoder_mfma(
    const float* __restrict__ q, const float* __restrict__ x,
    const short* __restrict__ w1p,
    const float* __restrict__ b1, const float* __restrict__ W2,
    const float* __restrict__ b2,
    const int* __restrict__ bidx, const int* __restrict__ y,
    float* __restrict__ sp, float* __restrict__ sn,
    int* __restrict__ cnt1, int* __restrict__ cnt0)
{
    __shared__ short As[3][16][64];   // bf16, 8B-slot XOR swizzle
    __shared__ float fold[4][16];
    const int t  = threadIdx.x;
    const int w  = t >> 6;            // wave 0..3
    const int l  = t & 63;
    const int lr = l & 15;            // A row / C col-in-tile
    const int lg = l >> 4;            // k-group 0..3
    const int r0 = blockIdx.x * 16;

    // A staging: thread t loads float4 = k [sslot*4, +4) of row srow
    const int srow  = t >> 4;
    const int sslot = t & 15;
    const int wslot = sslot ^ srow;   // physical 8B slot
    const float* qb = q + (size_t)(r0 + srow) * DD + sslot * 4;
    const float* xb = x + (size_t)(r0 + srow) * DD + sslot * 4;
    auto aptr = [&](int c) -> const float* {
        const int kc = c * BKC;
        return (kc < DD) ? (qb + kc) : (xb + (kc - DD));
    };
    auto stage = [&](int buf, const float4& v) {
        bf16x4 s;
        s[0] = f2bf(v.x); s[1] = f2bf(v.y); s[2] = f2bf(v.z); s[3] = f2bf(v.w);
        *(bf16x4*)&As[buf][srow][wslot * 4] = s;
    };

    // read slots (physical), 4 x ds_read_b64 per body
    const int p0 = ((2 * lg)     ^ lr) * 4;
    const int p1 = ((2 * lg + 1) ^ lr) * 4;
    const int p2 = ((2 * lg + 8) ^ lr) * 4;
    const int p3 = ((2 * lg + 9) ^ lr) * 4;

    // packed B base for this wave's tile pair (tile 2w), lane l
    const short* pB = w1p + ((size_t)(2 * w) * 64 + l) * 8;
    // element offsets: body c -> c*8192; odd 32-chunk: +4096; tile+1: +512
#define LOADB(c, x0, x1, x2, x3)                           \
    { const size_t e_ = (size_t)(c) * 8192;                \
      x0 = *(const bf16x8*)(pB + e_);                      \
      x1 = *(const bf16x8*)(pB + e_ + 4096);               \
      x2 = *(const bf16x8*)(pB + e_ + 512);                \
      x3 = *(const bf16x8*)(pB + e_ + 4096 + 512); }

    f32x4 acc0 = (f32x4)0.f, acc1 = (f32x4)0.f;
    bf16x8 bA0, bA1, bA2, bA3, bB0, bB1, bB2, bB3;

#define FRAGS_MFMA(rb, b0, b1_, b2_, b3_)                                   \
    { const short* ar = &As[rb][lr][0];                                     \
      bf16x4 g0 = *(const bf16x4*)(ar + p0);                                \
      bf16x4 g1 = *(const bf16x4*)(ar + p1);                                \
      bf16x4 g2 = *(const bf16x4*)(ar + p2);                                \
      bf16x4 g3 = *(const bf16x4*)(ar + p3);                                \
      bf16x8 aa0 = __builtin_shufflevector(g0, g1, 0,1,2,3,4,5,6,7);        \
      bf16x8 aa1 = __builtin_shufflevector(g2, g3, 0,1,2,3,4,5,6,7);        \
      acc0 = __builtin_amdgcn_mfma_f32_16x16x32_bf16(aa0, b0,  acc0, 0,0,0);\
      acc0 = __builtin_amdgcn_mfma_f32_16x16x32_bf16(aa1, b1_, acc0, 0,0,0);\
      acc1 = __builtin_amdgcn_mfma_f32_16x16x32_bf16(aa0, b2_, acc1, 0,0,0);\
      acc1 = __builtin_amdgcn_mfma_f32_16x16x32_bf16(aa1, b3_, acc1, 0,0,0); }

    // prologue: chunks 0,1 staged; A(2),A(3) in regs; B(0) in bA
    float4 t0 = *(const float4*)aptr(0);
    float4 t1 = *(const float4*)aptr(1);
    float4 rE = *(const float4*)aptr(2);
    float4 rO = *(const float4*)aptr(3);
    LOADB(0, bA0, bA1, bA2, bA3);
    stage(0, t0);
    stage(1, t1);
    __syncthreads();

    int rb = 0;
#pragma unroll 1
    for (int c = 0; c < NCH; c += 2) {
        // ---- even body: chunk c (B in bA), prefetch B(c+1)->bB ----
        { const int cn = c + 1 < NCH ? c + 1 : NCH - 1; LOADB(cn, bB0, bB1, bB2, bB3); }
        FRAGS_MFMA(rb, bA0, bA1, bA2, bA3);
        __syncthreads();
        { int wb = rb - 1; if (wb < 0) wb = 2;        // (rb+2)%3
          stage(wb, rE);                              // chunk c+2
          rE = *(const float4*)aptr(c + 4 < NCH ? c + 4 : NCH - 1); }
        rb = (rb == 2) ? 0 : rb + 1;
        // ---- odd body: chunk c+1 (B in bB), prefetch B(c+2)->bA ----
        { const int cn = c + 2 < NCH ? c + 2 : NCH - 1; LOADB(cn, bA0, bA1, bA2, bA3); }
        FRAGS_MFMA(rb, bB0, bB1, bB2, bB3);
        __syncthreads();
        { int wb = rb - 1; if (wb < 0) wb = 2;
          stage(wb, rO);                              // chunk c+3
          rO = *(const float4*)aptr(c + 5 < NCH ? c + 5 : NCH - 1); }
        rb = (rb == 2) ? 0 : rb + 1;
    }

    // epilogue: relu + W2 partial dot over this wave's 32 cols
    const int c0 = w * 32 + lr;
    const int c1 = c0 + 16;
    const float bb0 = (c0 < HH) ? b1[c0] : 0.f;
    const float ww0 = (c0 < HH) ? W2[c0] : 0.f;
    const float bb1 = (c1 < HH) ? b1[c1] : 0.f;
    const float ww1 = (c1 < HH) ? W2[c1] : 0.f;
#pragma unroll
    for (int r = 0; r < 4; ++r) {
        float v = fmaf(fmaxf(acc0[r] + bb0, 0.f), ww0,
                       fmaxf(acc1[r] + bb1, 0.f) * ww1);
        v += __shfl_xor(v, 1);
        v += __shfl_xor(v, 2);
        v += __shfl_xor(v, 4);
        v += __shfl_xor(v, 8);
        if (lr == 0) fold[w][lg * 4 + r] = v;
    }
    __syncthreads();
    if (t < 16) {
        const float sv = fold[0][t] + fold[1][t] + fold[2][t] + fold[3][t] + b2[0];
        const int i = r0 + t;
        const int g = bidx[i];
        if (y[i]) {
            int idx = atomicAdd(&cnt1[g], 1);
            if (idx < LCAP) sp[g * LCAP + idx] = sv;
        } else {
            int idx = atomicAdd(&cnt0[g], 1);
            if (idx < LCAP) sn[g * LCAP + idx] = sv;
        }
    }
#undef LOADB
#undef FRAGS_MFMA
}

// grid = NB*8 blocks; block (g, sl) handles pos indices p ≡ sl (mod 8).
__global__ __launch_bounds__(256) void pairsum_kernel(
    const float* __restrict__ sp, const float* __restrict__ sn,
    const int* __restrict__ cnt1, const int* __restrict__ cnt0,
    float* __restrict__ partial)
{
    __shared__ float lsn[LCAP];
    __shared__ float lsp[64];
    __shared__ float wsum[4];
    const int g  = blockIdx.x >> 3;
    const int sl = blockIdx.x & 7;
    const int t  = threadIdx.x;
    const int n1 = min(cnt1[g], LCAP);
    const int n0 = min(cnt0[g], LCAP);
    for (int j = t; j < n0; j += 256) lsn[j] = sn[g * LCAP + j];
    const int np = (n1 > sl) ? ((n1 - sl + 7) >> 3) : 0;
    for (int j = t; j < np; j += 256) lsp[j] = sp[g * LCAP + sl + j * 8];
    __syncthreads();
    float acc = 0.f;
    const int total = np * n0;
    for (int u = t; u < total; u += 256) {
        const int ip = u / n0;
        const int j  = u - ip * n0;
        const float d  = lsn[j] - lsp[ip];          // s_neg - s_pos
        const float ad = fabsf(d);
        const float z  = __builtin_exp2f(-ad * 1.44269504f);
        acc += fmaxf(d, 0.f) + __builtin_log2f(1.f + z) * 0.69314718f;
    }
#pragma unroll
    for (int off = 32; off > 0; off >>= 1) acc += __shfl_xor(acc, off, 64);
    const int wid = t >> 6, lane = t & 63;
    if (lane == 0) wsum[wid] = acc;
    __syncthreads();
    if (t == 0) partial[blockIdx.x] = wsum[0] + wsum[1] + wsum[2] + wsum[3];
}

__global__ __launch_bounds__(256) void finalize_kernel(
    const float* __restrict__ partial,
    const int* __restrict__ cnt1, const int* __restrict__ cnt0,
    float* __restrict__ out)
{
    __shared__ float ws_[4], wc_[4];
    const int t = threadIdx.x;
    float sv = partial[t];   // 256 entries
    float cv = 0.f;
    if (t < NB) cv = (float)min(cnt1[t], LCAP) * (float)min(cnt0[t], LCAP);
#pragma unroll
    for (int off = 32; off > 0; off >>= 1) {
        sv += __shfl_xor(sv, off, 64);
        cv += __shfl_xor(cv, off, 64);
    }
    const int wid = t >> 6, lane = t & 63;
    if (lane == 0) { ws_[wid] = sv; wc_[wid] = cv; }
    __syncthreads();
    if (t == 0)
        out[0] = (ws_[0] + ws_[1] + ws_[2] + ws_[3]) /
                 (wc_[0] + wc_[1] + wc_[2] + wc_[3]);
}

extern "C" void kernel_launch(void* const* d_in, const int* in_sizes, int n_in,
                              void* d_out, int out_size, void* d_ws, size_t ws_size,
                              hipStream_t stream)
{
    const int*   b  = (const int*)d_in[0];
    const float* q  = (const float*)d_in[1];
    const float* x  = (const float*)d_in[2];
    const int*   y  = (const int*)d_in[3];
    const float* W1 = (const float*)d_in[4];
    const float* b1 = (const float*)d_in[5];
    const float* W2 = (const float*)d_in[6];
    const float* b2 = (const float*)d_in[7];
    float* out = (float*)d_out;

    char* base = (char*)d_ws;
    short* w1p     = (short*)base;                       // 512 KB packed B
    float* sp      = (float*)(base + 524288);            // 64 KB
    float* sn      = (float*)(base + 524288 + 65536);    // 64 KB
    int*   cnt1    = (int*)(base + 524288 + 131072);     // 128 B
    int*   cnt0    = cnt1 + NB;                          // 128 B
    float* partial = (float*)(base + 524288 + 131072 + 256);  // 1 KB

    (void)hipMemsetAsync(cnt1, 0, 2 * NB * sizeof(int), stream);
    prep_w1p<<<KT / 32, 256, 0, stream>>>(W1, w1p);
    encoder_mfma<<<NN / 16, 256, 0, stream>>>(q, x, w1p, b1, W2, b2,
                                              b, y, sp, sn, cnt1, cnt0);
    pairsum_kernel<<<NB * 8, 256, 0, stream>>>(sp, sn, cnt1, cnt0, partial);
    finalize_kernel<<<1, 256, 0, stream>>>(partial, cnt1, cnt0, out);
}